// Round 4
// baseline (96.047 us; speedup 1.0000x reference)
//
#include <hip/hip_runtime.h>
#include <hip/hip_bf16.h>

// GlobalPointer logits: x = inputs@W+b -> split q/k per head -> RoPE(q) ->
// logits[b,h,m,n] = <q[b,m,h,:], k[b,n,h,:]> with mask+causal, /8.
// B=8 S=512 DIM=768 H=24 D=64. Output [8][24][512][512] f32.
// GEMM1 in MX-fp8 (e4m3, scale=1.0). Both GEMMs use swapped-operand MFMA so
// each lane's f32x4 spans 4 consecutive OUTPUT columns -> wide stores, in-lane RoPE.

typedef __bf16 bf16_t;
typedef __attribute__((ext_vector_type(8))) __bf16 bf16x8;
typedef __attribute__((ext_vector_type(4))) float f32x4;
typedef __attribute__((ext_vector_type(8))) int i32x8;

#define NEG_INF 1000000000000.0f

// ws layout (bytes)
#define WS_A8   0                  // inputs fp8 [4096][768]    : 3,145,728
#define WS_WT8  3145728            // W^T fp8 [3072][768]       : 2,359,296
#define WS_Q    5505024            // Q bf16 [8][24][512][64]   : 12,582,912
#define WS_K    18087936           // K bf16 [8][24][512][64]   : 12,582,912
#define WS_RC   30670848           // ropeC f32 [512][64]       : 131,072
#define WS_RS   30801920           // ropeS f32 [512][64]       : 131,072
// total 30,932,992 bytes

__device__ __forceinline__ unsigned short f2bf_bits(float x) {
  union { float f; unsigned u; } v; v.f = x;
  unsigned r = v.u + 0x7FFFu + ((v.u >> 16) & 1u);
  return (unsigned short)(r >> 16);
}

__device__ __forceinline__ int pack4_fp8(float a, float b, float c, float d) {
  int w = __builtin_amdgcn_cvt_pk_fp8_f32(a, b, 0, false);   // bytes 0,1
  w = __builtin_amdgcn_cvt_pk_fp8_f32(c, d, w, true);        // bytes 2,3
  return w;
}

#define GLD16(g, l) __builtin_amdgcn_global_load_lds( \
    (const __attribute__((address_space(1))) void*)(g), \
    (__attribute__((address_space(3))) void*)(l), 16, 0, 0)

// ---------------- fused prep ----------------
// blocks [0,768): inputs f32 -> fp8 (16 floats/thread)
// blocks [768,3072): W [768][3072] -> Wt [3072][768] fp8 (32x32 LDS transpose)
// blocks [3072,3200): RoPE tables ropeC/ropeS [512][64] f32
__global__ void prep_kernel(const float4* __restrict__ in, int4* __restrict__ outA,
                            const float* __restrict__ W, char* __restrict__ Wt8,
                            float* __restrict__ ropeC, float* __restrict__ ropeS) {
  __shared__ float s[32][33];
  if (blockIdx.x < 768) {
    int g = blockIdx.x * 256 + threadIdx.x;   // thread handles 16 floats
    float4 v0 = in[g * 4 + 0];
    float4 v1 = in[g * 4 + 1];
    float4 v2 = in[g * 4 + 2];
    float4 v3 = in[g * 4 + 3];
    int4 o;
    o.x = pack4_fp8(v0.x, v0.y, v0.z, v0.w);
    o.y = pack4_fp8(v1.x, v1.y, v1.z, v1.w);
    o.z = pack4_fp8(v2.x, v2.y, v2.z, v2.w);
    o.w = pack4_fp8(v3.x, v3.y, v3.z, v3.w);
    outA[g] = o;
  } else if (blockIdx.x < 3072) {
    int bid = blockIdx.x - 768;
    int n0 = (bid % 96) * 32, k0 = (bid / 96) * 32;
    int tx = threadIdx.x & 31, ty = threadIdx.x >> 5; // ty 0..7
#pragma unroll
    for (int r = 0; r < 4; ++r) {
      int k = k0 + ty + r * 8;
      s[ty + r * 8][tx] = W[(size_t)k * 3072 + n0 + tx];
    }
    __syncthreads();
    // write: thread (kx 0..7, tn 0..31) -> 4 consecutive k-bytes of row n0+tn
    int kx = threadIdx.x & 7, tn = threadIdx.x >> 3;
    int w = pack4_fp8(s[4 * kx + 0][tn], s[4 * kx + 1][tn],
                      s[4 * kx + 2][tn], s[4 * kx + 3][tn]);
    *(int*)(Wt8 + (size_t)(n0 + tn) * 768 + k0 + 4 * kx) = w;
  } else {
    int g = (blockIdx.x - 3072) * 256 + threadIdx.x;  // 32768 = [512][64]
    int sp = g >> 6, c = g & 63;
    float inv = exp2f((float)(c >> 1) * -0.4152410118609203f); // 10000^(-i/32)
    float ang = (float)sp * inv;
    float sn, cs;
    sincosf(ang, &sn, &cs);
    ropeC[g] = cs;
    ropeS[g] = sn;
  }
}

// ---------------- GEMM1 (MX-fp8): X = A(4096x768) * Wt^T(3072x768), +bias, RoPE(q), split ----
// 128x128 tile, 4 waves (2x2 of 64x64), BK=128, mfma_scale 16x16x128 f8f6f4.
// Swapped operands: mfma(Bfrag, Afrag) -> D tile has col=lane&15 = s-index,
// rows (lane>>4)*4+r = 4 consecutive c (output cols) -> in-lane RoPE + ushort4 stores.
// LDS rows 128B (8 x 16B slots); XOR swizzle slot ^= (row&7), both-sides. 2-phase dbuf.
__global__ __launch_bounds__(256) void gemm1_kernel(
    const char* __restrict__ A8, const char* __restrict__ Bt8,
    const float* __restrict__ bias,
    const float* __restrict__ ropeC, const float* __restrict__ ropeS,
    unsigned short* __restrict__ Qo, unsigned short* __restrict__ Ko) {
  __shared__ __align__(16) char As[2][128 * 128];
  __shared__ __align__(16) char Bs[2][128 * 128];
  const int tid = threadIdx.x;
  const int lane = tid & 63;
  const int wv = tid >> 6;
  const int wr = (wv >> 1) * 64;   // wave m-offset (s dim)
  const int wc = (wv & 1) * 64;    // wave n-offset (c dim)

  // bijective XCD swizzle over 768 blocks (768 % 8 == 0): 96 consecutive per XCD
  const int bid = blockIdx.x;
  const int swz = (bid & 7) * 96 + (bid >> 3);
  const int h = swz % 24;              // n-block == head
  const int m0 = (swz / 24) * 128;
  const int n0 = h * 128;

  f32x4 acc[4][4];   // acc[m16][n16], transposed-internal tiles
#pragma unroll
  for (int i = 0; i < 4; ++i)
#pragma unroll
    for (int j = 0; j < 4; ++j) acc[i][j] = (f32x4){0.f, 0.f, 0.f, 0.f};

  // staging: 32 chunks of 1KB (8 rows x 128B); wave w stages A/B chunks 4w..4w+3.
  const char* pA[4];
  const char* pB[4];
#pragma unroll
  for (int i = 0; i < 4; ++i) {
    int c = 4 * wv + i;
    int row = c * 8 + (lane >> 3);
    int srcslot = (lane & 7) ^ (row & 7);
    pA[i] = A8 + (size_t)(m0 + row) * 768 + srcslot * 16;
    pB[i] = Bt8 + (size_t)(n0 + row) * 768 + srcslot * 16;
  }

#define STAGE1(buf, k0) do { \
    _Pragma("unroll") \
    for (int i = 0; i < 4; ++i) { \
      GLD16(pA[i] + (k0), As[buf] + (4 * wv + i) * 1024); \
      GLD16(pB[i] + (k0), Bs[buf] + (4 * wv + i) * 1024); \
    } \
  } while (0)

#define COMPUTE1(buf) do { \
    const int t = lane >> 4; \
    i32x8 af[4], bfr[4]; \
    _Pragma("unroll") \
    for (int m16 = 0; m16 < 4; ++m16) { \
      int row = wr + m16 * 16 + (lane & 15); \
      int x = row & 7; \
      const char* rb = As[buf] + row * 128; \
      int4 lo = *(const int4*)(rb + ((2 * t) ^ x) * 16); \
      int4 hi = *(const int4*)(rb + ((2 * t + 1) ^ x) * 16); \
      af[m16] = (i32x8){lo.x, lo.y, lo.z, lo.w, hi.x, hi.y, hi.z, hi.w}; \
    } \
    _Pragma("unroll") \
    for (int n16 = 0; n16 < 4; ++n16) { \
      int row = wc + n16 * 16 + (lane & 15); \
      int x = row & 7; \
      const char* rb = Bs[buf] + row * 128; \
      int4 lo = *(const int4*)(rb + ((2 * t) ^ x) * 16); \
      int4 hi = *(const int4*)(rb + ((2 * t + 1) ^ x) * 16); \
      bfr[n16] = (i32x8){lo.x, lo.y, lo.z, lo.w, hi.x, hi.y, hi.z, hi.w}; \
    } \
    _Pragma("unroll") \
    for (int m16 = 0; m16 < 4; ++m16) \
      _Pragma("unroll") \
      for (int n16 = 0; n16 < 4; ++n16) \
        acc[m16][n16] = __builtin_amdgcn_mfma_scale_f32_16x16x128_f8f6f4( \
            bfr[n16], af[m16], acc[m16][n16], 0, 0, \
            0, 0x7F7F7F7F, 0, 0x7F7F7F7F); \
  } while (0)

  // 6 K-steps of 128. Prologue stage tile 0; 2-phase pipeline after.
  STAGE1(0, 0);
  __syncthreads();
#pragma unroll
  for (int kt = 0; kt < 5; ++kt) {
    const int cur = kt & 1;
    STAGE1(cur ^ 1, (kt + 1) * 128);
    COMPUTE1(cur);
    __syncthreads();
  }
  COMPUTE1(1);

  // epilogue: +bias, in-lane RoPE via tables, ushort4 stores.
  // lane holds: s = m0+wr+m16*16+(lane&15); c = wc+n16*16+(lane>>4)*4 + r (r=0..3)
#pragma unroll
  for (int n16 = 0; n16 < 4; ++n16) {
    int cbase = wc + n16 * 16 + ((lane >> 4) * 4);   // mult of 4
    bool isq = (cbase < 64);
    int d = cbase & 63;
    float4 bv = *(const float4*)&bias[h * 128 + cbase];
#pragma unroll
    for (int m16 = 0; m16 < 4; ++m16) {
      int sg = m0 + wr + m16 * 16 + (lane & 15);
      int sl = sg & 511, b = sg >> 9;
      f32x4 v = acc[m16][n16];
      float q0 = v[0] + bv.x, q1 = v[1] + bv.y, q2 = v[2] + bv.z, q3 = v[3] + bv.w;
      float r0 = q0, r1 = q1, r2 = q2, r3 = q3;
      if (isq) {
        float4 C = *(const float4*)&ropeC[sl * 64 + d];
        float4 S = *(const float4*)&ropeS[sl * 64 + d];
        r0 = q0 * C.x - q1 * S.x;
        r1 = q1 * C.y + q0 * S.y;
        r2 = q2 * C.z - q3 * S.z;
        r3 = q3 * C.w + q2 * S.w;
      }
      ushort4 o;
      o.x = f2bf_bits(r0); o.y = f2bf_bits(r1);
      o.z = f2bf_bits(r2); o.w = f2bf_bits(r3);
      size_t off = (((size_t)(b * 24 + h) * 512) + sl) * 64 + d;
      *(ushort4*)((isq ? Qo : Ko) + off) = o;
    }
  }
#undef STAGE1
#undef COMPUTE1
}

// ---------------- GEMM2: logits[bh] = Q(512x64) * K^T, mask/causal/scale ----------------
// Per block: 128x128 tile of one (b,h). Swapped operands: mfma(Kfrag, Qfrag) ->
// col=lane&15 = m, rows r = 4 consecutive n -> float4 output stores.
__global__ __launch_bounds__(256) void gemm2_kernel(
    const bf16_t* __restrict__ Q, const bf16_t* __restrict__ K,
    const float* __restrict__ mask, float* __restrict__ out) {
  __shared__ __align__(16) bf16_t Qs[128 * 64];
  __shared__ __align__(16) bf16_t Ks[128 * 64];
  const int tid = threadIdx.x;
  const int lane = tid & 63;
  const int wv = tid >> 6;
  const int wr = (wv >> 1) * 64;   // m offset
  const int wc = (wv & 1) * 64;    // n offset
  const int bh = blockIdx.z;
  const int b = bh / 24;
  const int m0 = blockIdx.y * 128;
  const int n0 = blockIdx.x * 128;
  const size_t base = (size_t)bh * 512 * 64;

  const int srow = lane >> 3;  // row within 8-row chunk (128B rows)
  const int sslot = lane & 7;
#pragma unroll
  for (int i = 0; i < 4; ++i) {
    int c = 4 * wv + i;                 // chunk 0..15 (8 rows each)
    int row = 8 * c + srow;
    int fslot = sslot ^ (row & 7);      // pre-swizzled source
    const bf16_t* gq = Q + base + (size_t)(m0 + row) * 64 + fslot * 8;
    const bf16_t* gk = K + base + (size_t)(n0 + row) * 64 + fslot * 8;
    GLD16(gq, Qs + c * 512);
    GLD16(gk, Ks + c * 512);
  }
  __syncthreads();

  f32x4 acc[4][4];   // acc[m16][n16], transposed-internal
#pragma unroll
  for (int i = 0; i < 4; ++i)
#pragma unroll
    for (int j = 0; j < 4; ++j) acc[i][j] = (f32x4){0.f, 0.f, 0.f, 0.f};

#pragma unroll
  for (int kk = 0; kk < 2; ++kk) {
    const int kslot = (lane >> 4) + kk * 4;
    bf16x8 af[4], bfr[4];
#pragma unroll
    for (int m16 = 0; m16 < 4; ++m16) {
      int arow = wr + m16 * 16 + (lane & 15);
      int sl = kslot ^ (arow & 7);
      af[m16] = *(const bf16x8*)(Qs + arow * 64 + sl * 8);
    }
#pragma unroll
    for (int n16 = 0; n16 < 4; ++n16) {
      int brow = wc + n16 * 16 + (lane & 15);
      int sl = kslot ^ (brow & 7);
      bfr[n16] = *(const bf16x8*)(Ks + brow * 64 + sl * 8);
    }
#pragma unroll
    for (int m16 = 0; m16 < 4; ++m16)
#pragma unroll
      for (int n16 = 0; n16 < 4; ++n16)
        acc[m16][n16] = __builtin_amdgcn_mfma_f32_16x16x32_bf16(
            bfr[n16], af[m16], acc[m16][n16], 0, 0, 0);
  }

  const float* mb = mask + (size_t)b * 512;
  float* ob = out + (size_t)bh * 512 * 512;
#pragma unroll
  for (int m16 = 0; m16 < 4; ++m16) {
    int mg = m0 + wr + m16 * 16 + (lane & 15);
    float mrv = mb[mg];
    float rbias = -NEG_INF * (1.0f - mrv);   // row-mask additive part
#pragma unroll
    for (int n16 = 0; n16 < 4; ++n16) {
      int nb = n0 + wc + n16 * 16 + ((lane >> 4) * 4);   // mult of 4
      float4 mc4 = *(const float4*)&mb[nb];
      f32x4 v = acc[m16][n16];
      float4 st;
      float x0 = v[0] * mrv + rbias;
      float x1 = v[1] * mrv + rbias;
      float x2 = v[2] * mrv + rbias;
      float x3 = v[3] * mrv + rbias;
      x0 = x0 * mc4.x - NEG_INF * (1.0f - mc4.x);
      x1 = x1 * mc4.y - NEG_INF * (1.0f - mc4.y);
      x2 = x2 * mc4.z - NEG_INF * (1.0f - mc4.z);
      x3 = x3 * mc4.w - NEG_INF * (1.0f - mc4.w);
      if (mg > nb + 0) x0 -= NEG_INF;
      if (mg > nb + 1) x1 -= NEG_INF;
      if (mg > nb + 2) x2 -= NEG_INF;
      if (mg > nb + 3) x3 -= NEG_INF;
      st.x = x0 * 0.125f; st.y = x1 * 0.125f;
      st.z = x2 * 0.125f; st.w = x3 * 0.125f;
      *(float4*)(ob + (size_t)mg * 512 + nb) = st;
    }
  }
}

extern "C" void kernel_launch(void* const* d_in, const int* in_sizes, int n_in,
                              void* d_out, int out_size, void* d_ws, size_t ws_size,
                              hipStream_t stream) {
  const float* inputs = (const float*)d_in[0];   // [8][512][768]
  const float* mask = (const float*)d_in[1];     // [8][512]
  const float* W = (const float*)d_in[2];        // [768][3072]
  const float* bias = (const float*)d_in[3];     // [3072]
  float* out = (float*)d_out;                    // [8][24][512][512]
  char* ws = (char*)d_ws;

  char* A8 = ws + WS_A8;
  char* Wt8 = ws + WS_WT8;
  unsigned short* Qb = (unsigned short*)(ws + WS_Q);
  unsigned short* Kb = (unsigned short*)(ws + WS_K);
  float* ropeC = (float*)(ws + WS_RC);
  float* ropeS = (float*)(ws + WS_RS);

  // inputs->fp8 (768) + W->W^T fp8 (2304) + RoPE tables (128), fused
  prep_kernel<<<3200, 256, 0, stream>>>((const float4*)inputs, (int4*)A8, W, Wt8,
                                        ropeC, ropeS);
  // X = A*W^T + b (MX-fp8), RoPE, split -> Q,K bf16 (768 blocks, XCD-swizzled)
  gemm1_kernel<<<768, 256, 0, stream>>>(A8, Wt8, bias, ropeC, ropeS, Qb, Kb);
  // logits
  gemm2_kernel<<<dim3(4, 4, 192), 256, 0, stream>>>((const bf16_t*)Qb,
                                                    (const bf16_t*)Kb, mask, out);
}